// Round 8
// baseline (213.200 us; speedup 1.0000x reference)
//
#include <hip/hip_runtime.h>

// PillarMaxPooling: Linear(10->64,nobias) -> BN1d(eval,eps=1e-3) -> ReLU ->
// segment_max -> clamp0.
//
// R8 (262us) -> R11 (216us): one-pass fixed-capacity (bucket,region) token
//   scatter + static-grid pool. R12-R14 (payload repack): measured dead end.
// R15 (211us): bucket width 100 -> NB=2000 (occ 66->72%) but pool time FLAT
//   at 84us. Conclusion: pool is NOT occupancy/BW/VALU-bound; it is bound by
//   per-CU outstanding line-misses on the random 40B gather (~80 lines per
//   64-token iter, ~32 MSHRs, ~350ns miss): occupancy & window size don't
//   matter (R9/R10/R15 all consistent). Only serial-chain trims remain.
// R16: (a) pool: software-pipeline the TOKEN load only (4B sequential read
//   for iter i+1 issued during iter i's compute) -- removes token latency
//   from the chain WITHOUT widening the 64-point gather window (R9 trap);
//   gather as float4+float4+float2 (3 VMEM ops, was 5x8B).
//   (b) scatter: SCHUNK 8192 (PPT 8, 245x1024 blocks): 4-token (16B) cell
//   runs, half the reservation atomics, half the per-block line touches.

#define C_IN   10
#define C_OUT  64
#define BPILL  100               // bucket width in pillars (magic-mul div)
#define MAXNBP 2048              // bucket arrays; supports M <= ~201k
#define NREG   8
#define SBLK   1024
#define SCHUNK 8192
#define PPT    (SCHUNK / SBLK)   // 8 points per thread
#define PBLK   512
#define TRASH  100               // acc row for masked lanes
#define SENT   ((unsigned)TRASH << 24)

typedef _Float16 half8  __attribute__((ext_vector_type(8)));
typedef float    f32x4  __attribute__((ext_vector_type(4)));
typedef float    f32x4a __attribute__((ext_vector_type(4), aligned(8)));

// Overflow fallback: direct per-point MLP + device atomicMax on out.
// Never taken for the bench distribution (>10 sigma margin).
__device__ __attribute__((noinline))
void fallback_point(int p, int m, const float* gf, const float* W,
                    const float* gamma, const float* beta,
                    const float* rmean, const float* rvar,
                    float* out, int* ovf) {
    atomicExch(ovf, 1);
    const float* x = gf + (size_t)p * C_IN;
    unsigned* o = (unsigned*)out + (size_t)m * C_OUT;
#pragma clang loop unroll(disable)
    for (int c = 0; c < C_OUT; ++c) {
        float is = gamma[c] * rsqrtf(rvar[c] + 1e-3f);
        float bb = fmaf(-rmean[c], is, beta[c]);
        float d = 0.f;
        for (int k = 0; k < C_IN; ++k) d = fmaf(x[k], W[k * C_OUT + c], d);
        atomicMax(o + c, __float_as_uint(fmaxf(fmaf(d, is, bb), 0.f)));
    }
}

// ---------- K1: one-pass token scatter into (bucket,region) cells ----------
__global__ __launch_bounds__(SBLK)
void k_scatter(const int* __restrict__ idx,
               const float* __restrict__ gf,
               const float* __restrict__ W,
               const float* __restrict__ gamma,
               const float* __restrict__ beta,
               const float* __restrict__ rmean,
               const float* __restrict__ rvar,
               int* __restrict__ cnt, int* __restrict__ ovf,
               unsigned* __restrict__ tok,
               float* __restrict__ out,
               int P, int NBpad, int CAPR) {
    __shared__ int lh[MAXNBP];
    __shared__ int rbase[MAXNBP];
    const int t = threadIdx.x;
    const int r = blockIdx.x & (NREG - 1);   // region ~ XCD (round-robin)

    for (int b = t; b < NBpad; b += SBLK) lh[b] = 0;
    __syncthreads();

    const int base = blockIdx.x * SCHUNK;
    int mm[PPT], rk[PPT];
#pragma unroll
    for (int i = 0; i < PPT; ++i) {
        int p = base + i * SBLK + t;
        mm[i] = (p < P) ? idx[p] : -1;
        rk[i] = (mm[i] >= 0) ? atomicAdd(&lh[mm[i] / BPILL], 1) : 0;
    }
    __syncthreads();

    int* crow = cnt + (size_t)r * NBpad;
    for (int b = t; b < NBpad; b += SBLK) {
        int h = lh[b];
        rbase[b] = h ? atomicAdd(&crow[b], h) : 0;
    }
    __syncthreads();

#pragma unroll
    for (int i = 0; i < PPT; ++i) {
        if (mm[i] < 0) continue;
        int p = base + i * SBLK + t;
        int b = mm[i] / BPILL;
        int ml = mm[i] - b * BPILL;          // idx % 100
        int slot = rbase[b] + rk[i];
        if (slot < CAPR) {
            tok[((size_t)b * NREG + r) * CAPR + slot] =
                (unsigned)p | ((unsigned)ml << 24);
        } else {
            fallback_point(p, mm[i], gf, W, gamma, beta, rmean, rvar, out, ovf);
        }
    }
}

// ---------- K2: pool — token-pipelined 64-point gather, MFMA, LDS max -------
__global__ __launch_bounds__(PBLK, 8)
void k_pool(const float* __restrict__ gf,
            const unsigned* __restrict__ tok,
            const int* __restrict__ cnt,
            const int* __restrict__ ovf,
            const float* __restrict__ W,
            const float* __restrict__ gamma,
            const float* __restrict__ beta,
            const float* __restrict__ rmean,
            const float* __restrict__ rvar,
            float* __restrict__ out, int M, int NBpad, int CAPR) {
    __shared__ unsigned int acc[(BPILL + 1) * 65];  // stride 65; row 100 = trash
    const int t = threadIdx.x;
    const int lane = t & 63;
    const int wv = t >> 6;                   // wave == region 0..7
    const int n = lane & 15;
    const int q = lane >> 4;

    for (int i = t; i < (BPILL + 1) * 65; i += PBLK) acc[i] = 0u;

    // B fragments: W rows k>=10 zeroed -> A K-padding free
    half8 bfrag[4];
    float inv[4], bia[4];
#pragma unroll
    for (int tt = 0; tt < 4; ++tt) {
        int c = tt * 16 + n;
#pragma unroll
        for (int j = 0; j < 8; ++j) {
            int k = q * 8 + j;
            bfrag[tt][j] = (k < C_IN) ? (_Float16)W[k * C_OUT + c] : (_Float16)0.f;
        }
        float is = gamma[c] * rsqrtf(rvar[c] + 1e-3f);
        inv[tt] = is;
        bia[tt] = fmaf(-rmean[c], is, beta[c]);
    }
    __syncthreads();

    const int blk = blockIdx.x;
    const int cn = min(cnt[(size_t)wv * NBpad + blk], CAPR);   // real count
    const unsigned* src0 = tok + ((size_t)blk * NREG + wv) * CAPR;

    // software-pipelined token: iter i+1's 4B sequential read issues during
    // iter i's compute; the 40B gather window stays 64 points (R9 lesson).
    unsigned vcur = (lane < cn) ? src0[lane] : SENT;

    for (int rb = 0; rb < cn; rb += 64) {
        unsigned vnext = (rb + 64 + lane < cn) ? src0[rb + 64 + lane] : SENT;

        // lane-per-point gather: float4 + float4 + float2 (rows 8B-aligned)
        const char* rowp = (const char*)gf + (size_t)(vcur & 0xFFFFFFu) * 40;
        f32x4a xa = *(const f32x4a*)rowp;
        f32x4a xb = *(const f32x4a*)(rowp + 16);
        float2 xc = *(const float2*)(rowp + 32);
        int u0 = __builtin_bit_cast(int, __builtin_amdgcn_cvt_pkrtz(xa.x, xa.y));
        int u1 = __builtin_bit_cast(int, __builtin_amdgcn_cvt_pkrtz(xa.z, xa.w));
        int u2 = __builtin_bit_cast(int, __builtin_amdgcn_cvt_pkrtz(xb.x, xb.y));
        int u3 = __builtin_bit_cast(int, __builtin_amdgcn_cvt_pkrtz(xb.z, xb.w));
        int u4 = __builtin_bit_cast(int, __builtin_amdgcn_cvt_pkrtz(xc.x, xc.y));

        const int ng = min(4, ((cn - rb) + 15) >> 4);   // 16-groups left
#pragma unroll
        for (int g = 0; g < 4; ++g) {
            if (g >= ng) break;              // wave-uniform
            const int sl = (g << 4) + n;     // source lane: point g*16+n
            int b0 = __shfl(u0, sl, 64);
            int b1 = __shfl(u1, sl, 64);
            int b2 = __shfl(u2, sl, 64);
            int b3 = __shfl(u3, sl, 64);
            int b4 = __shfl(u4, sl, 64);
            int4 a32;
            a32.x = (q == 0) ? b0 : ((q == 1) ? b4 : 0);
            a32.y = (q == 0) ? b1 : 0;
            a32.z = (q == 0) ? b2 : 0;
            a32.w = (q == 0) ? b3 : 0;
            half8 a = __builtin_bit_cast(half8, a32);
            f32x4 z = {0.f, 0.f, 0.f, 0.f};
            f32x4 d0 = __builtin_amdgcn_mfma_f32_16x16x32_f16(a, bfrag[0], z, 0, 0, 0);
            f32x4 d1 = __builtin_amdgcn_mfma_f32_16x16x32_f16(a, bfrag[1], z, 0, 0, 0);
            f32x4 d2 = __builtin_amdgcn_mfma_f32_16x16x32_f16(a, bfrag[2], z, 0, 0, 0);
            f32x4 d3 = __builtin_amdgcn_mfma_f32_16x16x32_f16(a, bfrag[3], z, 0, 0, 0);
#pragma unroll
            for (int r = 0; r < 4; ++r) {    // C row = 4q+r = point
                int mlr = __shfl((int)vcur, (g << 4) + (q << 2) + r, 64);
                int abase = (int)(((unsigned)mlr) >> 24) * 65 + n;   // ml row
                float h0 = fmaxf(fmaf(d0[r], inv[0], bia[0]), 0.f);
                float h1 = fmaxf(fmaf(d1[r], inv[1], bia[1]), 0.f);
                float h2 = fmaxf(fmaf(d2[r], inv[2], bia[2]), 0.f);
                float h3 = fmaxf(fmaf(d3[r], inv[3], bia[3]), 0.f);
                atomicMax(&acc[abase +  0], __float_as_uint(h0));
                atomicMax(&acc[abase + 16], __float_as_uint(h1));
                atomicMax(&acc[abase + 32], __float_as_uint(h2));
                atomicMax(&acc[abase + 48], __float_as_uint(h3));
            }
        }
        vcur = vnext;
    }
    __syncthreads();

    // coalesced writeback of 100 pillars x 64 channels; merge if overflow ran
    const int anyovf = ovf[0];
    const int mbase = blk * BPILL;
#pragma unroll
    for (int i = 0; i < (BPILL * C_OUT + PBLK - 1) / PBLK; ++i) {
        int wdx = i * PBLK + t;
        if (wdx >= BPILL * C_OUT) break;
        int row = wdx >> 6, c = wdx & 63;
        int m = mbase + row;
        if (m < M) {
            unsigned uv = acc[row * 65 + c];
            if (anyovf) atomicMax((unsigned*)out + (size_t)m * C_OUT + c, uv);
            else        out[(size_t)m * C_OUT + c] = __uint_as_float(uv);
        }
    }
}

extern "C" void kernel_launch(void* const* d_in, const int* in_sizes, int n_in,
                              void* d_out, int out_size, void* d_ws, size_t ws_size,
                              hipStream_t stream) {
    const float* gf    = (const float*)d_in[0];
    const int*   idx   = (const int*)  d_in[1];
    const float* W     = (const float*)d_in[3];
    const float* gamma = (const float*)d_in[4];
    const float* beta  = (const float*)d_in[5];
    const float* rmean = (const float*)d_in[6];
    const float* rvar  = (const float*)d_in[7];
    float*       out   = (float*)d_out;

    const int P  = in_sizes[0] / C_IN;
    const int M  = out_size / C_OUT;
    const int NB    = (M + BPILL - 1) / BPILL;      // 2000 for M=200k
    const int NBpad = (NB + 32) & ~31;              // 2016 (<= MAXNBP)
    const int E     = NREG * NBpad;                 // 16128 cells
    const int NSB   = (P + SCHUNK - 1) / SCHUNK;    // 245

    char* ws = (char*)d_ws;
    auto align256 = [](size_t x) { return (x + 255) & ~(size_t)255; };
    int* cnt = (int*)ws;  ws += align256((size_t)E * 4);
    int* ovf = (int*)ws;  ws += 256;
    unsigned* tok = (unsigned*)ws;

    // capacity per (bucket,region) cell; shrink if workspace is small
    int CAPR = 256;                                  // cell mean ~125, max ~180
    size_t fixed = (size_t)((char*)tok - (char*)cnt);
    size_t avail = (ws_size > fixed) ? ws_size - fixed : 0;
    while (CAPR > 128 && (size_t)E * CAPR * 4 > avail) CAPR -= 64;

    hipMemsetAsync(cnt, 0, fixed, stream);           // cnt + ovf in one memset

    k_scatter<<<NSB, SBLK, 0, stream>>>(idx, gf, W, gamma, beta, rmean, rvar,
                                        cnt, ovf, tok, out, P, NBpad, CAPR);
    k_pool   <<<NB,  PBLK, 0, stream>>>(gf, tok, cnt, ovf, W, gamma, beta,
                                        rmean, rvar, out, M, NBpad, CAPR);
}

// Round 9
// 209.933 us; speedup vs baseline: 1.0156x; 1.0156x over previous
//
#include <hip/hip_runtime.h>

// PillarMaxPooling: Linear(10->64,nobias) -> BN1d(eval,eps=1e-3) -> ReLU ->
// segment_max -> clamp0.
//
// R8 (262us) -> R11 (216us) -> R15 (211us): one-pass fixed-capacity
//   (bucket,region) token scatter + static-grid MFMA pool.
// R12-R14: payload repack = measured dead end (moves more bytes + extra trip).
// R15/R16: pool FLAT at ~83.5us under occupancy+6%, token pipelining, vec
//   gather => pool is MSHR-bound on the random 40B gather (~2.6M line-misses,
//   ~32/CU outstanding, ~350ns). Structural floor for the gather design.
// R17: attack the scatter's random 4B token stores (point-order phase 3 =
//   ~60 lines/wave RFO). In-LDS block counting sort: scan lh (per-bucket
//   counts) -> local positions; place (token,dst) at sorted LDS pos; write
//   out lane-major in sorted order -> consecutive lanes hit the same ~4-token
//   cell runs => ~16-24 lines/wave (~3x fewer store RFOs). LDS 80KB = 2
//   blocks/CU @1024thr = 32 waves = 100% occ. Pool unchanged.

#define C_IN   10
#define C_OUT  64
#define BPILL  100               // bucket width in pillars (magic-mul div)
#define MAXNBP 2048              // bucket arrays; supports M <= ~201k
#define NREG   8
#define SBLK   1024
#define SCHUNK 8192
#define PPT    (SCHUNK / SBLK)   // 8 points per thread
#define PBLK   512
#define TRASH  100               // acc row for masked lanes
#define SENT   ((unsigned)TRASH << 24)
#define SKIP   0xFFFFFFFFu

typedef _Float16 half8  __attribute__((ext_vector_type(8)));
typedef float    f32x4  __attribute__((ext_vector_type(4)));
typedef float    f32x4a __attribute__((ext_vector_type(4), aligned(8)));

// Overflow fallback: direct per-point MLP + device atomicMax on out.
// Never taken for the bench distribution (>10 sigma margin).
__device__ __attribute__((noinline))
void fallback_point(int p, int m, const float* gf, const float* W,
                    const float* gamma, const float* beta,
                    const float* rmean, const float* rvar,
                    float* out, int* ovf) {
    atomicExch(ovf, 1);
    const float* x = gf + (size_t)p * C_IN;
    unsigned* o = (unsigned*)out + (size_t)m * C_OUT;
#pragma clang loop unroll(disable)
    for (int c = 0; c < C_OUT; ++c) {
        float is = gamma[c] * rsqrtf(rvar[c] + 1e-3f);
        float bb = fmaf(-rmean[c], is, beta[c]);
        float d = 0.f;
        for (int k = 0; k < C_IN; ++k) d = fmaf(x[k], W[k * C_OUT + c], d);
        atomicMax(o + c, __float_as_uint(fmaxf(fmaf(d, is, bb), 0.f)));
    }
}

// ---------- K1: token scatter with in-LDS block sort for store compaction ---
// phase1: LDS hist, per-point rank from atomic return (held in regs)
// phase2: global reservation (1 atomicAdd per block,bucket) + scan partials
// phase3: block-level exclusive scan of lh -> local sorted positions
// phase4: place (token, global dst) at sorted LDS position
// phase5: lane-major write-out in sorted order (runs of ~4/cell -> coalesced)
__global__ __launch_bounds__(SBLK)
void k_scatter(const int* __restrict__ idx,
               const float* __restrict__ gf,
               const float* __restrict__ W,
               const float* __restrict__ gamma,
               const float* __restrict__ beta,
               const float* __restrict__ rmean,
               const float* __restrict__ rvar,
               int* __restrict__ cnt, int* __restrict__ ovf,
               unsigned* __restrict__ tok,
               float* __restrict__ out,
               int P, int NBpad, int CAPR) {
    __shared__ int lh[MAXNBP];               // counts -> (after scan) local base
    __shared__ int rbase[MAXNBP];            // global cell base for this block
    __shared__ unsigned stok[SCHUNK];        // sorted tokens
    __shared__ unsigned sdst[SCHUNK];        // global slot per sorted token
    const int t = threadIdx.x;
    const int r = blockIdx.x & (NREG - 1);   // region ~ XCD (round-robin)

    for (int b = t; b < MAXNBP; b += SBLK) lh[b] = 0;
    __syncthreads();

    const int base = blockIdx.x * SCHUNK;
    const int tot  = min(SCHUNK, P - base);  // valid points this block
    int mm[PPT], rk[PPT];
#pragma unroll
    for (int i = 0; i < PPT; ++i) {
        int p = base + i * SBLK + t;
        mm[i] = (p < P) ? idx[p] : -1;
        rk[i] = (mm[i] >= 0) ? atomicAdd(&lh[mm[i] / BPILL], 1) : 0;
    }
    __syncthreads();

    // ---- global reservation + scan partials (tmp aliases unused stok)
    int* tmp = (int*)stok;
    const int b0i = 2 * t, b1i = 2 * t + 1;
    const int s0 = (b0i < NBpad) ? lh[b0i] : 0;
    const int s1 = (b1i < NBpad) ? lh[b1i] : 0;
    tmp[t] = s0 + s1;
    int* crow = cnt + (size_t)r * NBpad;
    for (int b = t; b < NBpad; b += SBLK) {
        int h = lh[b];
        rbase[b] = h ? atomicAdd(&crow[b], h) : 0;
    }
    __syncthreads();

    // ---- 1024-wide Hillis-Steele inclusive scan of 2-bucket partials
#pragma unroll
    for (int off = 1; off < SBLK; off <<= 1) {
        int x = (t >= off) ? tmp[t - off] : 0;
        __syncthreads(); tmp[t] += x; __syncthreads();
    }
    const int ex = tmp[t] - (s0 + s1);       // exclusive over bucket pairs
    __syncthreads();                         // tmp reads done; stok reusable
    if (b0i < NBpad) lh[b0i] = ex;
    if (b1i < NBpad) lh[b1i] = ex + s0;      // lh := local sorted base
    __syncthreads();

    // ---- place tokens + precomputed global dst at sorted LDS positions
#pragma unroll
    for (int i = 0; i < PPT; ++i) {
        if (mm[i] < 0) continue;
        int p = base + i * SBLK + t;
        int b = mm[i] / BPILL;
        int ml = mm[i] - b * BPILL;          // idx % 100
        int pos  = lh[b] + rk[i];            // dense in [0, tot)
        int slot = rbase[b] + rk[i];
        stok[pos] = (unsigned)p | ((unsigned)ml << 24);
        if (slot < CAPR) {
            sdst[pos] = (unsigned)(((size_t)b * NREG + r) * CAPR + slot);
        } else {
            sdst[pos] = SKIP;
            fallback_point(p, mm[i], gf, W, gamma, beta, rmean, rvar, out, ovf);
        }
    }
    __syncthreads();

    // ---- lane-major write-out in sorted order: consecutive lanes hit the
    //      same ~4-token cell runs -> ~3x fewer store lines than point-order
#pragma unroll
    for (int k = 0; k < PPT; ++k) {
        int j = k * SBLK + t;
        if (j < tot) {
            unsigned d = sdst[j];
            if (d != SKIP) tok[d] = stok[j];
        }
    }
}

// ---------- K2: pool — token-pipelined 64-point gather, MFMA, LDS max -------
__global__ __launch_bounds__(PBLK, 8)
void k_pool(const float* __restrict__ gf,
            const unsigned* __restrict__ tok,
            const int* __restrict__ cnt,
            const int* __restrict__ ovf,
            const float* __restrict__ W,
            const float* __restrict__ gamma,
            const float* __restrict__ beta,
            const float* __restrict__ rmean,
            const float* __restrict__ rvar,
            float* __restrict__ out, int M, int NBpad, int CAPR) {
    __shared__ unsigned int acc[(BPILL + 1) * 65];  // stride 65; row 100 = trash
    const int t = threadIdx.x;
    const int lane = t & 63;
    const int wv = t >> 6;                   // wave == region 0..7
    const int n = lane & 15;
    const int q = lane >> 4;

    for (int i = t; i < (BPILL + 1) * 65; i += PBLK) acc[i] = 0u;

    // B fragments: W rows k>=10 zeroed -> A K-padding free
    half8 bfrag[4];
    float inv[4], bia[4];
#pragma unroll
    for (int tt = 0; tt < 4; ++tt) {
        int c = tt * 16 + n;
#pragma unroll
        for (int j = 0; j < 8; ++j) {
            int k = q * 8 + j;
            bfrag[tt][j] = (k < C_IN) ? (_Float16)W[k * C_OUT + c] : (_Float16)0.f;
        }
        float is = gamma[c] * rsqrtf(rvar[c] + 1e-3f);
        inv[tt] = is;
        bia[tt] = fmaf(-rmean[c], is, beta[c]);
    }
    __syncthreads();

    const int blk = blockIdx.x;
    const int cn = min(cnt[(size_t)wv * NBpad + blk], CAPR);   // real count
    const unsigned* src0 = tok + ((size_t)blk * NREG + wv) * CAPR;

    // software-pipelined token: iter i+1's 4B sequential read issues during
    // iter i's compute; the 40B gather window stays 64 points (R9 lesson).
    unsigned vcur = (lane < cn) ? src0[lane] : SENT;

    for (int rb = 0; rb < cn; rb += 64) {
        unsigned vnext = (rb + 64 + lane < cn) ? src0[rb + 64 + lane] : SENT;

        // lane-per-point gather: float4 + float4 + float2 (rows 8B-aligned)
        const char* rowp = (const char*)gf + (size_t)(vcur & 0xFFFFFFu) * 40;
        f32x4a xa = *(const f32x4a*)rowp;
        f32x4a xb = *(const f32x4a*)(rowp + 16);
        float2 xc = *(const float2*)(rowp + 32);
        int u0 = __builtin_bit_cast(int, __builtin_amdgcn_cvt_pkrtz(xa.x, xa.y));
        int u1 = __builtin_bit_cast(int, __builtin_amdgcn_cvt_pkrtz(xa.z, xa.w));
        int u2 = __builtin_bit_cast(int, __builtin_amdgcn_cvt_pkrtz(xb.x, xb.y));
        int u3 = __builtin_bit_cast(int, __builtin_amdgcn_cvt_pkrtz(xb.z, xb.w));
        int u4 = __builtin_bit_cast(int, __builtin_amdgcn_cvt_pkrtz(xc.x, xc.y));

        const int ng = min(4, ((cn - rb) + 15) >> 4);   // 16-groups left
#pragma unroll
        for (int g = 0; g < 4; ++g) {
            if (g >= ng) break;              // wave-uniform
            const int sl = (g << 4) + n;     // source lane: point g*16+n
            int b0 = __shfl(u0, sl, 64);
            int b1 = __shfl(u1, sl, 64);
            int b2 = __shfl(u2, sl, 64);
            int b3 = __shfl(u3, sl, 64);
            int b4 = __shfl(u4, sl, 64);
            int4 a32;
            a32.x = (q == 0) ? b0 : ((q == 1) ? b4 : 0);
            a32.y = (q == 0) ? b1 : 0;
            a32.z = (q == 0) ? b2 : 0;
            a32.w = (q == 0) ? b3 : 0;
            half8 a = __builtin_bit_cast(half8, a32);
            f32x4 z = {0.f, 0.f, 0.f, 0.f};
            f32x4 d0 = __builtin_amdgcn_mfma_f32_16x16x32_f16(a, bfrag[0], z, 0, 0, 0);
            f32x4 d1 = __builtin_amdgcn_mfma_f32_16x16x32_f16(a, bfrag[1], z, 0, 0, 0);
            f32x4 d2 = __builtin_amdgcn_mfma_f32_16x16x32_f16(a, bfrag[2], z, 0, 0, 0);
            f32x4 d3 = __builtin_amdgcn_mfma_f32_16x16x32_f16(a, bfrag[3], z, 0, 0, 0);
#pragma unroll
            for (int r = 0; r < 4; ++r) {    // C row = 4q+r = point
                int mlr = __shfl((int)vcur, (g << 4) + (q << 2) + r, 64);
                int abase = (int)(((unsigned)mlr) >> 24) * 65 + n;   // ml row
                float h0 = fmaxf(fmaf(d0[r], inv[0], bia[0]), 0.f);
                float h1 = fmaxf(fmaf(d1[r], inv[1], bia[1]), 0.f);
                float h2 = fmaxf(fmaf(d2[r], inv[2], bia[2]), 0.f);
                float h3 = fmaxf(fmaf(d3[r], inv[3], bia[3]), 0.f);
                atomicMax(&acc[abase +  0], __float_as_uint(h0));
                atomicMax(&acc[abase + 16], __float_as_uint(h1));
                atomicMax(&acc[abase + 32], __float_as_uint(h2));
                atomicMax(&acc[abase + 48], __float_as_uint(h3));
            }
        }
        vcur = vnext;
    }
    __syncthreads();

    // coalesced writeback of 100 pillars x 64 channels; merge if overflow ran
    const int anyovf = ovf[0];
    const int mbase = blk * BPILL;
#pragma unroll
    for (int i = 0; i < (BPILL * C_OUT + PBLK - 1) / PBLK; ++i) {
        int wdx = i * PBLK + t;
        if (wdx >= BPILL * C_OUT) break;
        int row = wdx >> 6, c = wdx & 63;
        int m = mbase + row;
        if (m < M) {
            unsigned uv = acc[row * 65 + c];
            if (anyovf) atomicMax((unsigned*)out + (size_t)m * C_OUT + c, uv);
            else        out[(size_t)m * C_OUT + c] = __uint_as_float(uv);
        }
    }
}

extern "C" void kernel_launch(void* const* d_in, const int* in_sizes, int n_in,
                              void* d_out, int out_size, void* d_ws, size_t ws_size,
                              hipStream_t stream) {
    const float* gf    = (const float*)d_in[0];
    const int*   idx   = (const int*)  d_in[1];
    const float* W     = (const float*)d_in[3];
    const float* gamma = (const float*)d_in[4];
    const float* beta  = (const float*)d_in[5];
    const float* rmean = (const float*)d_in[6];
    const float* rvar  = (const float*)d_in[7];
    float*       out   = (float*)d_out;

    const int P  = in_sizes[0] / C_IN;
    const int M  = out_size / C_OUT;
    const int NB    = (M + BPILL - 1) / BPILL;      // 2000 for M=200k
    const int NBpad = (NB + 32) & ~31;              // 2016 (<= MAXNBP)
    const int E     = NREG * NBpad;                 // 16128 cells
    const int NSB   = (P + SCHUNK - 1) / SCHUNK;    // 245

    char* ws = (char*)d_ws;
    auto align256 = [](size_t x) { return (x + 255) & ~(size_t)255; };
    int* cnt = (int*)ws;  ws += align256((size_t)E * 4);
    int* ovf = (int*)ws;  ws += 256;
    unsigned* tok = (unsigned*)ws;

    // capacity per (bucket,region) cell; shrink if workspace is small
    int CAPR = 256;                                  // cell mean ~125, max ~180
    size_t fixed = (size_t)((char*)tok - (char*)cnt);
    size_t avail = (ws_size > fixed) ? ws_size - fixed : 0;
    while (CAPR > 128 && (size_t)E * CAPR * 4 > avail) CAPR -= 64;

    hipMemsetAsync(cnt, 0, fixed, stream);           // cnt + ovf in one memset

    k_scatter<<<NSB, SBLK, 0, stream>>>(idx, gf, W, gamma, beta, rmean, rvar,
                                        cnt, ovf, tok, out, P, NBpad, CAPR);
    k_pool   <<<NB,  PBLK, 0, stream>>>(gf, tok, cnt, ovf, W, gamma, beta,
                                        rmean, rvar, out, M, NBpad, CAPR);
}